// Round 5
// baseline (514.107 us; speedup 1.0000x reference)
//
#include <hip/hip_runtime.h>
#include <stdint.h>

#define NROWS 32768   // B*H*W
#define CDIM  512
#define KCODES 1024
#define VC    512
#define LDP 72        // padded LDS leading dim (elements) — gemm3 A tile only

typedef unsigned short u16;
typedef unsigned long long u64;
using bf16x8 = __attribute__((ext_vector_type(8))) __bf16;
using f32x4  = __attribute__((ext_vector_type(4))) float;

__device__ __forceinline__ float bf2f(u16 u){
  union { unsigned int i; float f; } x; x.i = ((unsigned int)u) << 16; return x.f;
}
__device__ __forceinline__ u16 f2bf(float f){
  union { float f; unsigned int i; } x; x.f = f;
  unsigned int u = x.i;
  u += 0x7fffu + ((u >> 16) & 1u);   // RNE
  return (u16)(u >> 16);
}
__device__ __forceinline__ unsigned int pack2(u16 lo, u16 hi){
  return (unsigned int)lo | ((unsigned int)hi << 16);
}
__device__ __forceinline__ unsigned int fkey(float f){
  unsigned int u = __float_as_uint(f);
  return (u & 0x80000000u) ? ~u : (u | 0x80000000u);   // monotone sortable
}
__device__ __forceinline__ f32x4 mfma16(bf16x8 a, bf16x8 b, f32x4 c){
  return __builtin_amdgcn_mfma_f32_16x16x32_bf16(a, b, c, 0, 0, 0);
}
// async global->LDS, 16B per lane; LDS dest is wave-uniform base + lane*16
__device__ __forceinline__ void gload_lds16(const void* g, void* l){
  __builtin_amdgcn_global_load_lds(
      (const __attribute__((address_space(1))) unsigned int*)g,
      (__attribute__((address_space(3))) unsigned int*)l, 16, 0, 0);
}

// ---- K1: transpose x (B,C,H,W) -> xf bf16 (N, C); fused ||x||^2 partials -
// 64x64 tile, float4 loads, bf16x8 stores, XOR-swizzled LDS (col ^ (c&0x38)).
__global__ __launch_bounds__(256) void k_transpose_x(const float* __restrict__ x,
                                                     u16* __restrict__ xf,
                                                     float* __restrict__ rsum){
  __shared__ float tile[64 * 64];   // 16 KB, swizzled, no pad
  int b  = blockIdx.z;
  int p0 = blockIdx.x * 64;
  int c0 = blockIdx.y * 64;
  int t  = threadIdx.x;
  const float* xb = x + (size_t)b * CDIM * 4096 + (size_t)c0 * 4096 + p0;

  int pl4 = (t & 15) * 4;           // p offset for float4 load
#pragma unroll
  for (int i = 0; i < 4; i++){
    int cl = i * 16 + (t >> 4);
    float4 v = *(const float4*)(xb + (size_t)cl * 4096 + pl4);
    *(float4*)(tile + cl * 64 + (pl4 ^ (cl & 0x38))) = v;
  }
  __syncthreads();

  int cl0 = (t & 7) * 8;            // c base for this thread's 8 outputs
#pragma unroll
  for (int pass = 0; pass < 2; pass++){
    int pl = pass * 32 + (t >> 3);
    float v[8]; float s = 0.f;
#pragma unroll
    for (int j = 0; j < 8; j++){
      v[j] = tile[(cl0 + j) * 64 + (pl ^ cl0)];   // (cl0+j)&0x38 == cl0 for j<8
      s += v[j] * v[j];
    }
    uint4 o;
    o.x = pack2(f2bf(v[0]), f2bf(v[1]));
    o.y = pack2(f2bf(v[2]), f2bf(v[3]));
    o.z = pack2(f2bf(v[4]), f2bf(v[5]));
    o.w = pack2(f2bf(v[6]), f2bf(v[7]));
    *(uint4*)(xf + (size_t)(b * 4096 + p0 + pl) * CDIM + c0 + cl0) = o;
    // reduce s over the 8 lanes sharing this row (lane bits 0..2)
    s += __shfl_xor(s, 1, 64);
    s += __shfl_xor(s, 2, 64);
    s += __shfl_xor(s, 4, 64);
    if ((t & 7) == 0) atomicAdd(rsum + b * 4096 + p0 + pl, s);
  }
}

// ---- K2: merged {normalize noise_feature rows -> mn} + {transpose std} ---
// blocks 0..255: norm rows (4/block); blocks 256..767: std 32x32 tiles
__global__ __launch_bounds__(256) void k_prep(const float* __restrict__ in,
                                              u16* __restrict__ mn,
                                              const float* __restrict__ sd,
                                              u16* __restrict__ stdT){
  int t = threadIdx.x;
  if (blockIdx.x < 256){
    int row  = blockIdx.x * 4 + (t >> 6);
    int lane = t & 63;
    const float* r = in + (size_t)row * CDIM;
    float v[8]; float s = 0.f;
#pragma unroll
    for (int i = 0; i < 8; i++){ v[i] = r[lane + i * 64]; s += v[i] * v[i]; }
#pragma unroll
    for (int off = 32; off; off >>= 1) s += __shfl_xor(s, off, 64);
    float inv = 1.0f / fmaxf(sqrtf(s), 1e-12f);
#pragma unroll
    for (int i = 0; i < 8; i++) mn[(size_t)row * CDIM + lane + i * 64] = f2bf(v[i] * inv);
  } else {
    __shared__ float tile[32][33];
    int bid = blockIdx.x - 256;
    int k0 = (bid & 31) * 32;
    int v0 = (bid >> 5) * 32;
    int tx = t & 31, ty = t >> 5;
#pragma unroll
    for (int i = 0; i < 4; i++)
      tile[ty + i * 8][tx] = sd[(size_t)(k0 + ty + i * 8) * VC + v0 + tx];
    __syncthreads();
#pragma unroll
    for (int i = 0; i < 4; i++)
      stdT[(size_t)(v0 + ty + i * 8) * KCODES + k0 + tx] = f2bf(tile[tx][ty + i * 8]);
  }
}

// ---------------- K4: GEMM1 (xf @ mn^T) + packed atomicMax argmax ---------
__global__ __launch_bounds__(256) void k_gemm1_am(const u16* __restrict__ xf,
                                                  const u16* __restrict__ mn,
                                                  u64* __restrict__ packed){
  __shared__ __align__(16) u16 As[128 * 64];
  __shared__ __align__(16) u16 Bs[128 * 64];
  int tid  = threadIdx.x;
  int wave = tid >> 6, lane = tid & 63;
  int wr = wave >> 1, wc = wave & 1;
  int quad = lane >> 4, l15 = lane & 15;
  int c0 = blockIdx.x * 128, r0 = blockIdx.y * 128;

  int srow = lane >> 3, schunk = lane & 7;
  const u16* ag = xf + (size_t)(r0 + wave * 8 + srow) * CDIM + schunk * 8;
  const u16* bg = mn + (size_t)(c0 + wave * 8 + srow) * CDIM + schunk * 8;
  u16* adst = As + wave * 8 * 64;
  u16* bdst = Bs + wave * 8 * 64;

  f32x4 acc[4][4];
#pragma unroll
  for (int rt = 0; rt < 4; rt++)
#pragma unroll
    for (int ct = 0; ct < 4; ct++) acc[rt][ct] = (f32x4)(0.f);

  for (int k0 = 0; k0 < CDIM; k0 += 64){
#pragma unroll
    for (int i = 0; i < 4; i++){
      gload_lds16(ag + (size_t)i * 32 * CDIM + k0, adst + i * 32 * 64);
      gload_lds16(bg + (size_t)i * 32 * CDIM + k0, bdst + i * 32 * 64);
    }
    __syncthreads();
#pragma unroll
    for (int ks = 0; ks < 2; ks++){
      bf16x8 af[4], bfr[4];
#pragma unroll
      for (int rt = 0; rt < 4; rt++)
        af[rt] = *(const bf16x8*)(As + (wr * 64 + rt * 16 + l15) * 64 + ks * 32 + quad * 8);
#pragma unroll
      for (int ct = 0; ct < 4; ct++)
        bfr[ct] = *(const bf16x8*)(Bs + (wc * 64 + ct * 16 + l15) * 64 + ks * 32 + quad * 8);
#pragma unroll
      for (int rt = 0; rt < 4; rt++)
#pragma unroll
        for (int ct = 0; ct < 4; ct++)
          acc[rt][ct] = mfma16(af[rt], bfr[ct], acc[rt][ct]);
    }
    __syncthreads();
  }

#pragma unroll
  for (int rt = 0; rt < 4; rt++){
#pragma unroll
    for (int q = 0; q < 4; q++){
      float bv = acc[rt][0][q];
      int   bc = c0 + wc * 64 + l15;
#pragma unroll
      for (int ct = 1; ct < 4; ct++){
        float v = acc[rt][ct][q];
        int   c = c0 + wc * 64 + ct * 16 + l15;
        if (v > bv){ bv = v; bc = c; }          // ascending c: first wins ties
      }
#pragma unroll
      for (int off = 1; off <= 8; off <<= 1){
        float ov = __shfl_xor(bv, off, 64);
        int   oc = __shfl_xor(bc, off, 64);
        if (ov > bv || (ov == bv && oc < bc)){ bv = ov; bc = oc; }
      }
      if (l15 == 0){
        int rg = r0 + wr * 64 + rt * 16 + quad * 4 + q;
        u64 key = ((u64)fkey(bv) << 32) | (unsigned int)(~(unsigned int)bc);
        atomicMax(packed + rg, key);
      }
    }
  }
}

// ---------------- K5: per-code gather segment sum (reads packed directly) -
__global__ __launch_bounds__(256) void k_gather(const u64* __restrict__ packed,
                                                const u16* __restrict__ xf,
                                                float* __restrict__ esum,
                                                float* __restrict__ counts){
  __shared__ float part[4][CDIM];   // 8 KB
  __shared__ int   wcnt[4];
  int code = blockIdx.x;
  int tid = threadIdx.x, wave = tid >> 6, lane = tid & 63;
  float acc[8] = {0,0,0,0,0,0,0,0};
  int cnt = 0;
  for (int base = wave * 64; base < NROWS; base += 256){
    u64 pk = packed[base + lane];
    int cl = (int)(~(unsigned int)(pk & 0xffffffffull)) & (KCODES - 1);
    int match = (cl == code);
    u64 mask = __ballot(match);
    cnt += (int)__popcll(mask);
    while (mask){
      int b = __ffsll((long long)mask) - 1;
      mask &= mask - 1;
      int rr = base + b;
      uint4 v = *(const uint4*)(xf + (size_t)rr * CDIM + lane * 8);
      unsigned int w[4] = {v.x, v.y, v.z, v.w};
#pragma unroll
      for (int i = 0; i < 4; i++){
        acc[2 * i]     += bf2f((u16)(w[i] & 0xffffu));
        acc[2 * i + 1] += bf2f((u16)(w[i] >> 16));
      }
    }
  }
#pragma unroll
  for (int j = 0; j < 8; j++) part[wave][lane * 8 + j] = acc[j];
  if (lane == 0) wcnt[wave] = cnt;
  __syncthreads();
  for (int c = tid; c < CDIM; c += 256)
    esum[(size_t)code * CDIM + c] = part[0][c] + part[1][c] + part[2][c] + part[3][c];
  if (tid == 0) counts[code] = (float)(wcnt[0] + wcnt[1] + wcnt[2] + wcnt[3]);
}

// ---------------- K6: new_m = m*0.999 + mean*0.001; normalize -> mn2 bf16 -
__global__ __launch_bounds__(256) void k_newm(const float* __restrict__ m,
                                              const float* __restrict__ esum,
                                              const float* __restrict__ counts,
                                              u16* __restrict__ mn2){
  int row  = blockIdx.x * 4 + (threadIdx.x >> 6);
  int lane = threadIdx.x & 63;
  float cnt = counts[row];
  float sc  = 0.001f / (cnt + 1e-6f);
  float v[8]; float s = 0.f;
#pragma unroll
  for (int i = 0; i < 8; i++){
    int c = lane + i * 64;
    v[i] = m[(size_t)row * CDIM + c] * 0.999f + esum[(size_t)row * CDIM + c] * sc;
    s += v[i] * v[i];
  }
#pragma unroll
  for (int off = 32; off; off >>= 1) s += __shfl_xor(s, off, 64);
  float inv = 1.0f / fmaxf(sqrtf(s), 1e-12f);
#pragma unroll
  for (int i = 0; i < 8; i++) mn2[(size_t)row * CDIM + lane + i * 64] = f2bf(v[i] * inv);
}

// ---------------- K7: GEMM2 score2 = (xf @ mn2^T) / ||x||row --------------
// rinv computed inline from rsum; fused per-(row,64col) softmax partials
__global__ __launch_bounds__(256) void k_gemm2(const u16* __restrict__ xf,
                                               const u16* __restrict__ mn2,
                                               const float* __restrict__ rsum,
                                               float* __restrict__ score2,
                                               float* __restrict__ pmax,
                                               float* __restrict__ psum){
  __shared__ __align__(16) u16 As[128 * 64];
  __shared__ __align__(16) u16 Bs[128 * 64];
  int tid  = threadIdx.x;
  int wave = tid >> 6, lane = tid & 63;
  int wr = wave >> 1, wc = wave & 1;
  int quad = lane >> 4, l15 = lane & 15;
  int c0 = blockIdx.x * 128, r0 = blockIdx.y * 128;

  int srow = lane >> 3, schunk = lane & 7;
  const u16* ag = xf  + (size_t)(r0 + wave * 8 + srow) * CDIM + schunk * 8;
  const u16* bg = mn2 + (size_t)(c0 + wave * 8 + srow) * CDIM + schunk * 8;
  u16* adst = As + wave * 8 * 64;
  u16* bdst = Bs + wave * 8 * 64;

  f32x4 acc[4][4];
#pragma unroll
  for (int rt = 0; rt < 4; rt++)
#pragma unroll
    for (int ct = 0; ct < 4; ct++) acc[rt][ct] = (f32x4)(0.f);

  for (int k0 = 0; k0 < CDIM; k0 += 64){
#pragma unroll
    for (int i = 0; i < 4; i++){
      gload_lds16(ag + (size_t)i * 32 * CDIM + k0, adst + i * 32 * 64);
      gload_lds16(bg + (size_t)i * 32 * CDIM + k0, bdst + i * 32 * 64);
    }
    __syncthreads();
#pragma unroll
    for (int ks = 0; ks < 2; ks++){
      bf16x8 af[4], bfr[4];
#pragma unroll
      for (int rt = 0; rt < 4; rt++)
        af[rt] = *(const bf16x8*)(As + (wr * 64 + rt * 16 + l15) * 64 + ks * 32 + quad * 8);
#pragma unroll
      for (int ct = 0; ct < 4; ct++)
        bfr[ct] = *(const bf16x8*)(Bs + (wc * 64 + ct * 16 + l15) * 64 + ks * 32 + quad * 8);
#pragma unroll
      for (int rt = 0; rt < 4; rt++)
#pragma unroll
        for (int ct = 0; ct < 4; ct++)
          acc[rt][ct] = mfma16(af[rt], bfr[ct], acc[rt][ct]);
    }
    __syncthreads();
  }

#pragma unroll
  for (int rt = 0; rt < 4; rt++){
#pragma unroll
    for (int q = 0; q < 4; q++){
      int grow = r0 + wr * 64 + rt * 16 + quad * 4 + q;
      float rv = 1.0f / fmaxf(sqrtf(rsum[grow]), 1e-12f);
      float v0 = acc[rt][0][q] * rv;
      float v1 = acc[rt][1][q] * rv;
      float v2 = acc[rt][2][q] * rv;
      float v3 = acc[rt][3][q] * rv;
      float* so = score2 + (size_t)grow * KCODES + c0 + wc * 64 + l15;
      so[0]  = v0;
      so[16] = v1;
      so[32] = v2;
      so[48] = v3;
      float mx = fmaxf(fmaxf(v0, v1), fmaxf(v2, v3));
#pragma unroll
      for (int off = 1; off <= 8; off <<= 1) mx = fmaxf(mx, __shfl_xor(mx, off, 64));
      float s = __expf(v0 - mx) + __expf(v1 - mx) + __expf(v2 - mx) + __expf(v3 - mx);
#pragma unroll
      for (int off = 1; off <= 8; off <<= 1) s += __shfl_xor(s, off, 64);
      if (l15 == 0){
        int pi = grow * 16 + blockIdx.x * 2 + wc;
        pmax[pi] = mx;
        psum[pi] = s;
      }
    }
  }
}

// ---------------- K8: combine 16 partials/row -> rowmax, rsinv ------------
__global__ __launch_bounds__(256) void k_softcomb(const float* __restrict__ pmax,
                                                  const float* __restrict__ psum,
                                                  float* __restrict__ rowmax,
                                                  float* __restrict__ rsinv){
  int row = blockIdx.x * 256 + threadIdx.x;
  const float* pm = pmax + (size_t)row * 16;
  const float* ps = psum + (size_t)row * 16;
  float M = pm[0];
#pragma unroll
  for (int i = 1; i < 16; i++) M = fmaxf(M, pm[i]);
  float S = 0.f;
#pragma unroll
  for (int i = 0; i < 16; i++) S += ps[i] * __expf(pm[i] - M);
  rowmax[row] = M;
  rsinv[row]  = 1.0f / S;
}

// ---------------- K9: out = softmax(score2) @ std  (128x512 tile, 512 thr)
// Single column pass (BN = VC = 512): score2 read exactly ONCE.
// B tile linear [512][64] via global_load_lds; A tile reg-staged (exp) padded
__global__ __launch_bounds__(512) void k_gemm3(const float* __restrict__ score2,
                                               const float* __restrict__ rowmax,
                                               const float* __restrict__ rsinv,
                                               const u16* __restrict__ stdT,
                                               float* __restrict__ out){
  __shared__ __align__(16) u16 As[128 * LDP];   // 18 KB, padded (ds_write side)
  __shared__ __align__(16) u16 Bs[512 * 64];    // 64 KB, linear (global_load_lds)
  int tid  = threadIdx.x;
  int wave = tid >> 6, lane = tid & 63;
  int wr = wave >> 2, wcol = wave & 3;          // 2 x 4 wave grid (64r x 128c tiles)
  int quad = lane >> 4, l15 = lane & 15;
  int r0 = blockIdx.x * 128;
  int arow = tid >> 2, aq = tid & 3;            // A: 4 thr/row, 16 elems each

  int srow = lane >> 3, schunk = lane & 7;
  const u16* bg = stdT + (size_t)(wave * 8 + srow) * KCODES + schunk * 8;
  u16* bdst = Bs + wave * 8 * 64;

  float rmax = rowmax[r0 + arow];
  float rs   = rsinv [r0 + arow];

  f32x4 acc[4][8];
#pragma unroll
  for (int rt = 0; rt < 4; rt++)
#pragma unroll
    for (int ct = 0; ct < 8; ct++) acc[rt][ct] = (f32x4)(0.f);

  const float* ag = score2 + (size_t)(r0 + arow) * KCODES + aq * 16;

  for (int k0 = 0; k0 < KCODES; k0 += 64){
#pragma unroll
    for (int i = 0; i < 8; i++)
      gload_lds16(bg + (size_t)i * 64 * KCODES + k0, bdst + i * 64 * 64);
#pragma unroll
    for (int j = 0; j < 2; j++){
      float4 a = *(const float4*)(ag + k0 + j * 8);
      float4 b = *(const float4*)(ag + k0 + j * 8 + 4);
      uint4 o;
      o.x = pack2(f2bf(__expf(a.x - rmax) * rs), f2bf(__expf(a.y - rmax) * rs));
      o.y = pack2(f2bf(__expf(a.z - rmax) * rs), f2bf(__expf(a.w - rmax) * rs));
      o.z = pack2(f2bf(__expf(b.x - rmax) * rs), f2bf(__expf(b.y - rmax) * rs));
      o.w = pack2(f2bf(__expf(b.z - rmax) * rs), f2bf(__expf(b.w - rmax) * rs));
      *(uint4*)(As + arow * LDP + aq * 16 + j * 8) = o;
    }
    __syncthreads();
#pragma unroll
    for (int ks = 0; ks < 2; ks++){
      bf16x8 af[4];
#pragma unroll
      for (int rt = 0; rt < 4; rt++)
        af[rt] = *(const bf16x8*)(As + (wr * 64 + rt * 16 + l15) * LDP + ks * 32 + quad * 8);
#pragma unroll
      for (int ct = 0; ct < 8; ct++){
        bf16x8 bv = *(const bf16x8*)(Bs + (wcol * 128 + ct * 16 + l15) * 64 + ks * 32 + quad * 8);
#pragma unroll
        for (int rt = 0; rt < 4; rt++)
          acc[rt][ct] = mfma16(af[rt], bv, acc[rt][ct]);
      }
    }
    __syncthreads();
  }
#pragma unroll
  for (int rt = 0; rt < 4; rt++){
#pragma unroll
    for (int q = 0; q < 4; q++){
      int grow = r0 + wr * 64 + rt * 16 + quad * 4 + q;
#pragma unroll
      for (int ct = 0; ct < 8; ct++){
        int gcol = wcol * 128 + ct * 16 + l15;
        out[(size_t)grow * VC + gcol] = acc[rt][ct][q];
      }
    }
  }
}

// ---------------- launch ---------------------------------------------------
extern "C" void kernel_launch(void* const* d_in, const int* in_sizes, int n_in,
                              void* d_out, int out_size, void* d_ws, size_t ws_size,
                              hipStream_t stream){
  (void)in_sizes; (void)n_in; (void)out_size; (void)ws_size;
  const float* x      = (const float*)d_in[0];
  const float* m      = (const float*)d_in[1];
  const float* stdmat = (const float*)d_in[2];
  float* out    = (float*)d_out;
  float* score2 = out + (size_t)NROWS * VC;     // outputs: (out, score2)

  char* ws = (char*)d_ws;
  u16*   xf     = (u16*)  (ws + 0);             // 33,554,432 B
  u16*   mn     = (u16*)  (ws + 33554432);      //  1,048,576 B
  u16*   mn2    = (u16*)  (ws + 34603008);      //  1,048,576 B
  u16*   stdT   = (u16*)  (ws + 35651584);      //  1,048,576 B
  u64*   packed = (u64*)  (ws + 36831232);      //    262,144 B
  float* esum   = (float*)(ws + 37224448);      //  2,097,152 B
  float* counts = (float*)(ws + 39321600);      //      4,096 B
  float* rowmax = (float*)(ws + 39325696);      //    131,072 B (aliased: rsum early)
  float* rsinv  = (float*)(ws + 39456768);      //    131,072 B
  float* pmax   = (float*)(ws + 39587840);      //  2,097,152 B
  float* psum   = (float*)(ws + 41684992);      //  2,097,152 B
  float* rsum   = rowmax;                       // disjoint lifetime: rsum is
                                                // consumed by k_gemm2 before
                                                // k_softcomb writes rowmax

  hipMemsetAsync(packed, 0, (size_t)NROWS * 8, stream);  // key=0 is identity
  hipMemsetAsync(rsum,   0, (size_t)NROWS * 4, stream);

  k_transpose_x  <<<dim3(64, 8, 8), 256, 0, stream>>>(x, xf, rsum);
  k_prep         <<<768, 256, 0, stream>>>(m, mn, stdmat, stdT);
  k_gemm1_am     <<<dim3(KCODES / 128, NROWS / 128), 256, 0, stream>>>(xf, mn, packed);
  k_gather       <<<KCODES, 256, 0, stream>>>(packed, xf, esum, counts);
  k_newm         <<<KCODES / 4, 256, 0, stream>>>(m, esum, counts, mn2);
  k_gemm2        <<<dim3(KCODES / 128, NROWS / 128), 256, 0, stream>>>(xf, mn2, rsum, score2, pmax, psum);
  k_softcomb     <<<NROWS / 256, 256, 0, stream>>>(pmax, psum, rowmax, rsinv);
  k_gemm3        <<<NROWS / 128, 512, 0, stream>>>(score2, rowmax, rsinv, stdT, out);
}

// Round 6
// 463.210 us; speedup vs baseline: 1.1099x; 1.1099x over previous
//
#include <hip/hip_runtime.h>
#include <stdint.h>

#define NROWS 32768   // B*H*W
#define CDIM  512
#define KCODES 1024
#define VC    512
#define LDP 72        // padded LDS leading dim (elements) — gemm3 A tile only

typedef unsigned short u16;
typedef unsigned long long u64;
using bf16x8 = __attribute__((ext_vector_type(8))) __bf16;
using f32x4  = __attribute__((ext_vector_type(4))) float;

__device__ __forceinline__ float bf2f(u16 u){
  union { unsigned int i; float f; } x; x.i = ((unsigned int)u) << 16; return x.f;
}
__device__ __forceinline__ u16 f2bf(float f){
  union { float f; unsigned int i; } x; x.f = f;
  unsigned int u = x.i;
  u += 0x7fffu + ((u >> 16) & 1u);   // RNE
  return (u16)(u >> 16);
}
__device__ __forceinline__ unsigned int pack2(u16 lo, u16 hi){
  return (unsigned int)lo | ((unsigned int)hi << 16);
}
__device__ __forceinline__ unsigned int fkey(float f){
  unsigned int u = __float_as_uint(f);
  return (u & 0x80000000u) ? ~u : (u | 0x80000000u);   // monotone sortable
}
__device__ __forceinline__ f32x4 mfma16(bf16x8 a, bf16x8 b, f32x4 c){
  return __builtin_amdgcn_mfma_f32_16x16x32_bf16(a, b, c, 0, 0, 0);
}
// async global->LDS, 16B per lane; LDS dest is wave-uniform base + lane*16
__device__ __forceinline__ void gload_lds16(const void* g, void* l){
  __builtin_amdgcn_global_load_lds(
      (const __attribute__((address_space(1))) unsigned int*)g,
      (__attribute__((address_space(3))) unsigned int*)l, 16, 0, 0);
}

// ---- K1: transpose x (B,C,H,W) -> xf bf16 (N, C); fused ||x||^2 partials -
// 64x64 tile, float4 loads, bf16x8 stores, XOR-swizzled LDS (col ^ (c&0x38)).
__global__ __launch_bounds__(256) void k_transpose_x(const float* __restrict__ x,
                                                     u16* __restrict__ xf,
                                                     float* __restrict__ rsum){
  __shared__ float tile[64 * 64];   // 16 KB, swizzled, no pad
  int b  = blockIdx.z;
  int p0 = blockIdx.x * 64;
  int c0 = blockIdx.y * 64;
  int t  = threadIdx.x;
  const float* xb = x + (size_t)b * CDIM * 4096 + (size_t)c0 * 4096 + p0;

  int pl4 = (t & 15) * 4;           // p offset for float4 load
#pragma unroll
  for (int i = 0; i < 4; i++){
    int cl = i * 16 + (t >> 4);
    float4 v = *(const float4*)(xb + (size_t)cl * 4096 + pl4);
    *(float4*)(tile + cl * 64 + (pl4 ^ (cl & 0x38))) = v;
  }
  __syncthreads();

  int cl0 = (t & 7) * 8;            // c base for this thread's 8 outputs
#pragma unroll
  for (int pass = 0; pass < 2; pass++){
    int pl = pass * 32 + (t >> 3);
    float v[8]; float s = 0.f;
#pragma unroll
    for (int j = 0; j < 8; j++){
      v[j] = tile[(cl0 + j) * 64 + (pl ^ cl0)];   // (cl0+j)&0x38 == cl0 for j<8
      s += v[j] * v[j];
    }
    uint4 o;
    o.x = pack2(f2bf(v[0]), f2bf(v[1]));
    o.y = pack2(f2bf(v[2]), f2bf(v[3]));
    o.z = pack2(f2bf(v[4]), f2bf(v[5]));
    o.w = pack2(f2bf(v[6]), f2bf(v[7]));
    *(uint4*)(xf + (size_t)(b * 4096 + p0 + pl) * CDIM + c0 + cl0) = o;
    // reduce s over the 8 lanes sharing this row (lane bits 0..2)
    s += __shfl_xor(s, 1, 64);
    s += __shfl_xor(s, 2, 64);
    s += __shfl_xor(s, 4, 64);
    if ((t & 7) == 0) atomicAdd(rsum + b * 4096 + p0 + pl, s);
  }
}

// ---- K2: merged {normalize noise_feature rows -> mn} + {transpose std} ---
// blocks 0..255: norm rows (4/block); blocks 256..767: std 32x32 tiles
__global__ __launch_bounds__(256) void k_prep(const float* __restrict__ in,
                                              u16* __restrict__ mn,
                                              const float* __restrict__ sd,
                                              u16* __restrict__ stdT){
  int t = threadIdx.x;
  if (blockIdx.x < 256){
    int row  = blockIdx.x * 4 + (t >> 6);
    int lane = t & 63;
    const float* r = in + (size_t)row * CDIM;
    float v[8]; float s = 0.f;
#pragma unroll
    for (int i = 0; i < 8; i++){ v[i] = r[lane + i * 64]; s += v[i] * v[i]; }
#pragma unroll
    for (int off = 32; off; off >>= 1) s += __shfl_xor(s, off, 64);
    float inv = 1.0f / fmaxf(sqrtf(s), 1e-12f);
#pragma unroll
    for (int i = 0; i < 8; i++) mn[(size_t)row * CDIM + lane + i * 64] = f2bf(v[i] * inv);
  } else {
    __shared__ float tile[32][33];
    int bid = blockIdx.x - 256;
    int k0 = (bid & 31) * 32;
    int v0 = (bid >> 5) * 32;
    int tx = t & 31, ty = t >> 5;
#pragma unroll
    for (int i = 0; i < 4; i++)
      tile[ty + i * 8][tx] = sd[(size_t)(k0 + ty + i * 8) * VC + v0 + tx];
    __syncthreads();
#pragma unroll
    for (int i = 0; i < 4; i++)
      stdT[(size_t)(v0 + ty + i * 8) * KCODES + k0 + tx] = f2bf(tile[tx][ty + i * 8]);
  }
}

// ---------------- K4: GEMM1 (xf @ mn^T) + packed atomicMax argmax ---------
// 256x128 tile, 512 thr (8 waves as 4x2), BK=64, m97 2-phase structure.
__global__ __launch_bounds__(512, 4) void k_gemm1_am(const u16* __restrict__ xf,
                                                     const u16* __restrict__ mn,
                                                     u64* __restrict__ packed){
  __shared__ __align__(16) u16 As[256 * 64];   // 32 KB
  __shared__ __align__(16) u16 Bs[128 * 64];   // 16 KB
  int tid  = threadIdx.x;
  int wave = tid >> 6, lane = tid & 63;
  int wr = wave >> 1, wc = wave & 1;           // 4 x 2 wave grid
  int quad = lane >> 4, l15 = lane & 15;
  int c0 = blockIdx.x * 128, r0 = blockIdx.y * 256;

  int srow = lane >> 3, schunk = lane & 7;
  const u16* ag = xf + (size_t)(r0 + wave * 8 + srow) * CDIM + schunk * 8;
  const u16* bg = mn + (size_t)(c0 + wave * 8 + srow) * CDIM + schunk * 8;
  u16* adst = As + wave * 8 * 64;
  u16* bdst = Bs + wave * 8 * 64;

  f32x4 acc[4][4];
#pragma unroll
  for (int rt = 0; rt < 4; rt++)
#pragma unroll
    for (int ct = 0; ct < 4; ct++) acc[rt][ct] = (f32x4)(0.f);

  for (int k0 = 0; k0 < CDIM; k0 += 64){
#pragma unroll
    for (int i = 0; i < 4; i++)
      gload_lds16(ag + (size_t)(i * 64) * CDIM + k0, adst + i * 64 * 64);
#pragma unroll
    for (int j = 0; j < 2; j++)
      gload_lds16(bg + (size_t)(j * 64) * CDIM + k0, bdst + j * 64 * 64);
    __syncthreads();
#pragma unroll
    for (int ks = 0; ks < 2; ks++){
      bf16x8 af[4], bfr[4];
#pragma unroll
      for (int rt = 0; rt < 4; rt++)
        af[rt] = *(const bf16x8*)(As + (wr * 64 + rt * 16 + l15) * 64 + ks * 32 + quad * 8);
#pragma unroll
      for (int ct = 0; ct < 4; ct++)
        bfr[ct] = *(const bf16x8*)(Bs + (wc * 64 + ct * 16 + l15) * 64 + ks * 32 + quad * 8);
#pragma unroll
      for (int rt = 0; rt < 4; rt++)
#pragma unroll
        for (int ct = 0; ct < 4; ct++)
          acc[rt][ct] = mfma16(af[rt], bfr[ct], acc[rt][ct]);
    }
    __syncthreads();
  }

#pragma unroll
  for (int rt = 0; rt < 4; rt++){
#pragma unroll
    for (int q = 0; q < 4; q++){
      float bv = acc[rt][0][q];
      int   bc = c0 + wc * 64 + l15;
#pragma unroll
      for (int ct = 1; ct < 4; ct++){
        float v = acc[rt][ct][q];
        int   c = c0 + wc * 64 + ct * 16 + l15;
        if (v > bv){ bv = v; bc = c; }          // ascending c: first wins ties
      }
#pragma unroll
      for (int off = 1; off <= 8; off <<= 1){
        float ov = __shfl_xor(bv, off, 64);
        int   oc = __shfl_xor(bc, off, 64);
        if (ov > bv || (ov == bv && oc < bc)){ bv = ov; bc = oc; }
      }
      if (l15 == 0){
        int rg = r0 + wr * 64 + rt * 16 + quad * 4 + q;
        u64 key = ((u64)fkey(bv) << 32) | (unsigned int)(~(unsigned int)bc);
        atomicMax(packed + rg, key);
      }
    }
  }
}

// ---------------- K5: per-code gather segment sum (reads packed directly) -
__global__ __launch_bounds__(256) void k_gather(const u64* __restrict__ packed,
                                                const u16* __restrict__ xf,
                                                float* __restrict__ esum,
                                                float* __restrict__ counts){
  __shared__ float part[4][CDIM];   // 8 KB
  __shared__ int   wcnt[4];
  int code = blockIdx.x;
  int tid = threadIdx.x, wave = tid >> 6, lane = tid & 63;
  float acc[8] = {0,0,0,0,0,0,0,0};
  int cnt = 0;
  for (int base = wave * 64; base < NROWS; base += 256){
    u64 pk = packed[base + lane];
    int cl = (int)(~(unsigned int)(pk & 0xffffffffull)) & (KCODES - 1);
    int match = (cl == code);
    u64 mask = __ballot(match);
    cnt += (int)__popcll(mask);
    while (mask){
      int b = __ffsll((long long)mask) - 1;
      mask &= mask - 1;
      int rr = base + b;
      uint4 v = *(const uint4*)(xf + (size_t)rr * CDIM + lane * 8);
      unsigned int w[4] = {v.x, v.y, v.z, v.w};
#pragma unroll
      for (int i = 0; i < 4; i++){
        acc[2 * i]     += bf2f((u16)(w[i] & 0xffffu));
        acc[2 * i + 1] += bf2f((u16)(w[i] >> 16));
      }
    }
  }
#pragma unroll
  for (int j = 0; j < 8; j++) part[wave][lane * 8 + j] = acc[j];
  if (lane == 0) wcnt[wave] = cnt;
  __syncthreads();
  for (int c = tid; c < CDIM; c += 256)
    esum[(size_t)code * CDIM + c] = part[0][c] + part[1][c] + part[2][c] + part[3][c];
  if (tid == 0) counts[code] = (float)(wcnt[0] + wcnt[1] + wcnt[2] + wcnt[3]);
}

// ---------------- K6: new_m = m*0.999 + mean*0.001; normalize -> mn2 bf16 -
__global__ __launch_bounds__(256) void k_newm(const float* __restrict__ m,
                                              const float* __restrict__ esum,
                                              const float* __restrict__ counts,
                                              u16* __restrict__ mn2){
  int row  = blockIdx.x * 4 + (threadIdx.x >> 6);
  int lane = threadIdx.x & 63;
  float cnt = counts[row];
  float sc  = 0.001f / (cnt + 1e-6f);
  float v[8]; float s = 0.f;
#pragma unroll
  for (int i = 0; i < 8; i++){
    int c = lane + i * 64;
    v[i] = m[(size_t)row * CDIM + c] * 0.999f + esum[(size_t)row * CDIM + c] * sc;
    s += v[i] * v[i];
  }
#pragma unroll
  for (int off = 32; off; off >>= 1) s += __shfl_xor(s, off, 64);
  float inv = 1.0f / fmaxf(sqrtf(s), 1e-12f);
#pragma unroll
  for (int i = 0; i < 8; i++) mn2[(size_t)row * CDIM + lane + i * 64] = f2bf(v[i] * inv);
}

// ---------------- K7: GEMM2 score2 = (xf @ mn2^T) / ||x||row --------------
// 256x128 tile, 512 thr; rinv inline from rsum; fused softmax partials
__global__ __launch_bounds__(512, 4) void k_gemm2(const u16* __restrict__ xf,
                                                  const u16* __restrict__ mn2,
                                                  const float* __restrict__ rsum,
                                                  float* __restrict__ score2,
                                                  float* __restrict__ pmax,
                                                  float* __restrict__ psum){
  __shared__ __align__(16) u16 As[256 * 64];   // 32 KB
  __shared__ __align__(16) u16 Bs[128 * 64];   // 16 KB
  int tid  = threadIdx.x;
  int wave = tid >> 6, lane = tid & 63;
  int wr = wave >> 1, wc = wave & 1;           // 4 x 2 wave grid
  int quad = lane >> 4, l15 = lane & 15;
  int c0 = blockIdx.x * 128, r0 = blockIdx.y * 256;

  int srow = lane >> 3, schunk = lane & 7;
  const u16* ag = xf  + (size_t)(r0 + wave * 8 + srow) * CDIM + schunk * 8;
  const u16* bg = mn2 + (size_t)(c0 + wave * 8 + srow) * CDIM + schunk * 8;
  u16* adst = As + wave * 8 * 64;
  u16* bdst = Bs + wave * 8 * 64;

  f32x4 acc[4][4];
#pragma unroll
  for (int rt = 0; rt < 4; rt++)
#pragma unroll
    for (int ct = 0; ct < 4; ct++) acc[rt][ct] = (f32x4)(0.f);

  for (int k0 = 0; k0 < CDIM; k0 += 64){
#pragma unroll
    for (int i = 0; i < 4; i++)
      gload_lds16(ag + (size_t)(i * 64) * CDIM + k0, adst + i * 64 * 64);
#pragma unroll
    for (int j = 0; j < 2; j++)
      gload_lds16(bg + (size_t)(j * 64) * CDIM + k0, bdst + j * 64 * 64);
    __syncthreads();
#pragma unroll
    for (int ks = 0; ks < 2; ks++){
      bf16x8 af[4], bfr[4];
#pragma unroll
      for (int rt = 0; rt < 4; rt++)
        af[rt] = *(const bf16x8*)(As + (wr * 64 + rt * 16 + l15) * 64 + ks * 32 + quad * 8);
#pragma unroll
      for (int ct = 0; ct < 4; ct++)
        bfr[ct] = *(const bf16x8*)(Bs + (wc * 64 + ct * 16 + l15) * 64 + ks * 32 + quad * 8);
#pragma unroll
      for (int rt = 0; rt < 4; rt++)
#pragma unroll
        for (int ct = 0; ct < 4; ct++)
          acc[rt][ct] = mfma16(af[rt], bfr[ct], acc[rt][ct]);
    }
    __syncthreads();
  }

#pragma unroll
  for (int rt = 0; rt < 4; rt++){
#pragma unroll
    for (int q = 0; q < 4; q++){
      int grow = r0 + wr * 64 + rt * 16 + quad * 4 + q;
      float rv = 1.0f / fmaxf(sqrtf(rsum[grow]), 1e-12f);
      float v0 = acc[rt][0][q] * rv;
      float v1 = acc[rt][1][q] * rv;
      float v2 = acc[rt][2][q] * rv;
      float v3 = acc[rt][3][q] * rv;
      float* so = score2 + (size_t)grow * KCODES + c0 + wc * 64 + l15;
      so[0]  = v0;
      so[16] = v1;
      so[32] = v2;
      so[48] = v3;
      float mx = fmaxf(fmaxf(v0, v1), fmaxf(v2, v3));
#pragma unroll
      for (int off = 1; off <= 8; off <<= 1) mx = fmaxf(mx, __shfl_xor(mx, off, 64));
      float s = __expf(v0 - mx) + __expf(v1 - mx) + __expf(v2 - mx) + __expf(v3 - mx);
#pragma unroll
      for (int off = 1; off <= 8; off <<= 1) s += __shfl_xor(s, off, 64);
      if (l15 == 0){
        int pi = grow * 16 + blockIdx.x * 2 + wc;
        pmax[pi] = mx;
        psum[pi] = s;
      }
    }
  }
}

// ---------------- K8: combine 16 partials/row -> rowmax, rsinv ------------
__global__ __launch_bounds__(256) void k_softcomb(const float* __restrict__ pmax,
                                                  const float* __restrict__ psum,
                                                  float* __restrict__ rowmax,
                                                  float* __restrict__ rsinv){
  int row = blockIdx.x * 256 + threadIdx.x;
  const float* pm = pmax + (size_t)row * 16;
  const float* ps = psum + (size_t)row * 16;
  float M = pm[0];
#pragma unroll
  for (int i = 1; i < 16; i++) M = fmaxf(M, pm[i]);
  float S = 0.f;
#pragma unroll
  for (int i = 0; i < 16; i++) S += ps[i] * __expf(pm[i] - M);
  rowmax[row] = M;
  rsinv[row]  = 1.0f / S;
}

// ---------------- K9: out = softmax(score2) @ std  (128x256 tile, 512 thr)
// R4 version: 2 column passes, 50 KB LDS, 2 blocks/CU.
__global__ __launch_bounds__(512) void k_gemm3(const float* __restrict__ score2,
                                               const float* __restrict__ rowmax,
                                               const float* __restrict__ rsinv,
                                               const u16* __restrict__ stdT,
                                               float* __restrict__ out){
  __shared__ __align__(16) u16 As[128 * LDP];   // 18 KB, padded (ds_write side)
  __shared__ __align__(16) u16 Bs[256 * 64];    // 32 KB, linear (global_load_lds)
  int tid  = threadIdx.x;
  int wave = tid >> 6, lane = tid & 63;
  int wr = wave >> 2, wcol = wave & 3;          // 2 x 4 wave grid
  int quad = lane >> 4, l15 = lane & 15;
  int c0 = blockIdx.x * 256, r0 = blockIdx.y * 128;
  int arow = tid >> 2, aq = tid & 3;            // A: 4 thr/row, 16 elems each

  int srow = lane >> 3, schunk = lane & 7;
  const u16* bg = stdT + (size_t)(c0 + wave * 8 + srow) * KCODES + schunk * 8;
  u16* bdst = Bs + wave * 8 * 64;

  float rmax = rowmax[r0 + arow];
  float rs   = rsinv [r0 + arow];

  f32x4 acc[4][4];
#pragma unroll
  for (int rt = 0; rt < 4; rt++)
#pragma unroll
    for (int ct = 0; ct < 4; ct++) acc[rt][ct] = (f32x4)(0.f);

  const float* ag = score2 + (size_t)(r0 + arow) * KCODES + aq * 16;

  for (int k0 = 0; k0 < KCODES; k0 += 64){
#pragma unroll
    for (int i = 0; i < 4; i++)
      gload_lds16(bg + (size_t)i * 64 * KCODES + k0, bdst + i * 64 * 64);
#pragma unroll
    for (int j = 0; j < 2; j++){
      float4 a = *(const float4*)(ag + k0 + j * 8);
      float4 b = *(const float4*)(ag + k0 + j * 8 + 4);
      uint4 o;
      o.x = pack2(f2bf(__expf(a.x - rmax) * rs), f2bf(__expf(a.y - rmax) * rs));
      o.y = pack2(f2bf(__expf(a.z - rmax) * rs), f2bf(__expf(a.w - rmax) * rs));
      o.z = pack2(f2bf(__expf(b.x - rmax) * rs), f2bf(__expf(b.y - rmax) * rs));
      o.w = pack2(f2bf(__expf(b.z - rmax) * rs), f2bf(__expf(b.w - rmax) * rs));
      *(uint4*)(As + arow * LDP + aq * 16 + j * 8) = o;
    }
    __syncthreads();
#pragma unroll
    for (int ks = 0; ks < 2; ks++){
      bf16x8 af[4], bfr[4];
#pragma unroll
      for (int rt = 0; rt < 4; rt++)
        af[rt] = *(const bf16x8*)(As + (wr * 64 + rt * 16 + l15) * LDP + ks * 32 + quad * 8);
#pragma unroll
      for (int ct = 0; ct < 4; ct++)
        bfr[ct] = *(const bf16x8*)(Bs + (wcol * 64 + ct * 16 + l15) * 64 + ks * 32 + quad * 8);
#pragma unroll
      for (int rt = 0; rt < 4; rt++)
#pragma unroll
        for (int ct = 0; ct < 4; ct++)
          acc[rt][ct] = mfma16(af[rt], bfr[ct], acc[rt][ct]);
    }
    __syncthreads();
  }
#pragma unroll
  for (int rt = 0; rt < 4; rt++){
#pragma unroll
    for (int q = 0; q < 4; q++){
      int grow = r0 + wr * 64 + rt * 16 + quad * 4 + q;
#pragma unroll
      for (int ct = 0; ct < 4; ct++){
        int gcol = c0 + wcol * 64 + ct * 16 + l15;
        out[(size_t)grow * VC + gcol] = acc[rt][ct][q];
      }
    }
  }
}

// ---------------- launch ---------------------------------------------------
extern "C" void kernel_launch(void* const* d_in, const int* in_sizes, int n_in,
                              void* d_out, int out_size, void* d_ws, size_t ws_size,
                              hipStream_t stream){
  (void)in_sizes; (void)n_in; (void)out_size; (void)ws_size;
  const float* x      = (const float*)d_in[0];
  const float* m      = (const float*)d_in[1];
  const float* stdmat = (const float*)d_in[2];
  float* out    = (float*)d_out;
  float* score2 = out + (size_t)NROWS * VC;     // outputs: (out, score2)

  char* ws = (char*)d_ws;
  u16*   xf     = (u16*)  (ws + 0);             // 33,554,432 B
  u16*   mn     = (u16*)  (ws + 33554432);      //  1,048,576 B
  u16*   mn2    = (u16*)  (ws + 34603008);      //  1,048,576 B
  u16*   stdT   = (u16*)  (ws + 35651584);      //  1,048,576 B
  u64*   packed = (u64*)  (ws + 36831232);      //    262,144 B
  float* esum   = (float*)(ws + 37224448);      //  2,097,152 B
  float* counts = (float*)(ws + 39321600);      //      4,096 B
  float* rowmax = (float*)(ws + 39325696);      //    131,072 B (aliased: rsum early)
  float* rsinv  = (float*)(ws + 39456768);      //    131,072 B
  float* pmax   = (float*)(ws + 39587840);      //  2,097,152 B
  float* psum   = (float*)(ws + 41684992);      //  2,097,152 B
  float* rsum   = rowmax;                       // disjoint lifetime: rsum is
                                                // consumed by k_gemm2 before
                                                // k_softcomb writes rowmax

  hipMemsetAsync(packed, 0, (size_t)NROWS * 8, stream);  // key=0 is identity
  hipMemsetAsync(rsum,   0, (size_t)NROWS * 4, stream);

  k_transpose_x  <<<dim3(64, 8, 8), 256, 0, stream>>>(x, xf, rsum);
  k_prep         <<<768, 256, 0, stream>>>(m, mn, stdmat, stdT);
  k_gemm1_am     <<<dim3(KCODES / 128, NROWS / 256), 512, 0, stream>>>(xf, mn, packed);
  k_gather       <<<KCODES, 256, 0, stream>>>(packed, xf, esum, counts);
  k_newm         <<<KCODES / 4, 256, 0, stream>>>(m, esum, counts, mn2);
  k_gemm2        <<<dim3(KCODES / 128, NROWS / 256), 512, 0, stream>>>(xf, mn2, rsum, score2, pmax, psum);
  k_softcomb     <<<NROWS / 256, 256, 0, stream>>>(pmax, psum, rowmax, rsinv);
  k_gemm3        <<<dim3(VC / 256, NROWS / 128), 512, 0, stream>>>(score2, rowmax, rsinv, stdT, out);
}

// Round 7
// 437.346 us; speedup vs baseline: 1.1755x; 1.0591x over previous
//
#include <hip/hip_runtime.h>
#include <stdint.h>

#define NROWS 32768   // B*H*W
#define CDIM  512
#define KCODES 1024
#define VC    512
#define LDP 72        // padded LDS leading dim (elements) — gemm3 A tile only

typedef unsigned short u16;
typedef unsigned long long u64;
using bf16x8 = __attribute__((ext_vector_type(8))) __bf16;
using f32x4  = __attribute__((ext_vector_type(4))) float;

__device__ __forceinline__ float bf2f(u16 u){
  union { unsigned int i; float f; } x; x.i = ((unsigned int)u) << 16; return x.f;
}
__device__ __forceinline__ u16 f2bf(float f){
  union { float f; unsigned int i; } x; x.f = f;
  unsigned int u = x.i;
  u += 0x7fffu + ((u >> 16) & 1u);   // RNE
  return (u16)(u >> 16);
}
__device__ __forceinline__ unsigned int pack2(u16 lo, u16 hi){
  return (unsigned int)lo | ((unsigned int)hi << 16);
}
__device__ __forceinline__ unsigned int fkey(float f){
  unsigned int u = __float_as_uint(f);
  return (u & 0x80000000u) ? ~u : (u | 0x80000000u);   // monotone sortable
}
__device__ __forceinline__ f32x4 mfma16(bf16x8 a, bf16x8 b, f32x4 c){
  return __builtin_amdgcn_mfma_f32_16x16x32_bf16(a, b, c, 0, 0, 0);
}
// async global->LDS, 16B per lane; LDS dest is wave-uniform base + lane*16
__device__ __forceinline__ void gload_lds16(const void* g, void* l){
  __builtin_amdgcn_global_load_lds(
      (const __attribute__((address_space(1))) unsigned int*)g,
      (__attribute__((address_space(3))) unsigned int*)l, 16, 0, 0);
}

// ---- K1: transpose x (B,C,H,W) -> xf bf16 (N, C); fused ||x||^2 partials -
__global__ __launch_bounds__(256) void k_transpose_x(const float* __restrict__ x,
                                                     u16* __restrict__ xf,
                                                     float* __restrict__ rsum){
  __shared__ float tile[64 * 64];   // 16 KB, swizzled, no pad
  int b  = blockIdx.z;
  int p0 = blockIdx.x * 64;
  int c0 = blockIdx.y * 64;
  int t  = threadIdx.x;
  const float* xb = x + (size_t)b * CDIM * 4096 + (size_t)c0 * 4096 + p0;

  int pl4 = (t & 15) * 4;           // p offset for float4 load
#pragma unroll
  for (int i = 0; i < 4; i++){
    int cl = i * 16 + (t >> 4);
    float4 v = *(const float4*)(xb + (size_t)cl * 4096 + pl4);
    *(float4*)(tile + cl * 64 + (pl4 ^ (cl & 0x38))) = v;
  }
  __syncthreads();

  int cl0 = (t & 7) * 8;            // c base for this thread's 8 outputs
#pragma unroll
  for (int pass = 0; pass < 2; pass++){
    int pl = pass * 32 + (t >> 3);
    float v[8]; float s = 0.f;
#pragma unroll
    for (int j = 0; j < 8; j++){
      v[j] = tile[(cl0 + j) * 64 + (pl ^ cl0)];   // (cl0+j)&0x38 == cl0 for j<8
      s += v[j] * v[j];
    }
    uint4 o;
    o.x = pack2(f2bf(v[0]), f2bf(v[1]));
    o.y = pack2(f2bf(v[2]), f2bf(v[3]));
    o.z = pack2(f2bf(v[4]), f2bf(v[5]));
    o.w = pack2(f2bf(v[6]), f2bf(v[7]));
    *(uint4*)(xf + (size_t)(b * 4096 + p0 + pl) * CDIM + c0 + cl0) = o;
    s += __shfl_xor(s, 1, 64);
    s += __shfl_xor(s, 2, 64);
    s += __shfl_xor(s, 4, 64);
    if ((t & 7) == 0) atomicAdd(rsum + b * 4096 + p0 + pl, s);
  }
}

// ---- K2: merged {normalize noise_feature rows -> mn} + {transpose std} ---
__global__ __launch_bounds__(256) void k_prep(const float* __restrict__ in,
                                              u16* __restrict__ mn,
                                              const float* __restrict__ sd,
                                              u16* __restrict__ stdT){
  int t = threadIdx.x;
  if (blockIdx.x < 256){
    int row  = blockIdx.x * 4 + (t >> 6);
    int lane = t & 63;
    const float* r = in + (size_t)row * CDIM;
    float v[8]; float s = 0.f;
#pragma unroll
    for (int i = 0; i < 8; i++){ v[i] = r[lane + i * 64]; s += v[i] * v[i]; }
#pragma unroll
    for (int off = 32; off; off >>= 1) s += __shfl_xor(s, off, 64);
    float inv = 1.0f / fmaxf(sqrtf(s), 1e-12f);
#pragma unroll
    for (int i = 0; i < 8; i++) mn[(size_t)row * CDIM + lane + i * 64] = f2bf(v[i] * inv);
  } else {
    __shared__ float tile[32][33];
    int bid = blockIdx.x - 256;
    int k0 = (bid & 31) * 32;
    int v0 = (bid >> 5) * 32;
    int tx = t & 31, ty = t >> 5;
#pragma unroll
    for (int i = 0; i < 4; i++)
      tile[ty + i * 8][tx] = sd[(size_t)(k0 + ty + i * 8) * VC + v0 + tx];
    __syncthreads();
#pragma unroll
    for (int i = 0; i < 4; i++)
      stdT[(size_t)(v0 + ty + i * 8) * KCODES + k0 + tx] = f2bf(tile[tx][ty + i * 8]);
  }
}

// ---------------- K4: GEMM1 (xf @ mn^T) + packed atomicMax argmax ---------
// 256x128 tile, 512 thr (8 waves as 4x2), XCD-aware swizzle (col fastest).
__global__ __launch_bounds__(512, 4) void k_gemm1_am(const u16* __restrict__ xf,
                                                     const u16* __restrict__ mn,
                                                     u64* __restrict__ packed){
  __shared__ __align__(16) u16 As[256 * 64];   // 32 KB
  __shared__ __align__(16) u16 Bs[128 * 64];   // 16 KB
  int tid  = threadIdx.x;
  int wave = tid >> 6, lane = tid & 63;
  int wr = wave >> 1, wc = wave & 1;           // 4 x 2 wave grid
  int quad = lane >> 4, l15 = lane & 15;
  // swizzle: nwg=1024; XCD k owns 16 contiguous row-panels across all 8 col-tiles
  int bid  = blockIdx.y * gridDim.x + blockIdx.x;
  int work = (bid & 7) * 128 + (bid >> 3);
  int r0 = (work >> 3) * 256;
  int c0 = (work & 7) * 128;

  int srow = lane >> 3, schunk = lane & 7;
  const u16* ag = xf + (size_t)(r0 + wave * 8 + srow) * CDIM + schunk * 8;
  const u16* bg = mn + (size_t)(c0 + wave * 8 + srow) * CDIM + schunk * 8;
  u16* adst = As + wave * 8 * 64;
  u16* bdst = Bs + wave * 8 * 64;

  f32x4 acc[4][4];
#pragma unroll
  for (int rt = 0; rt < 4; rt++)
#pragma unroll
    for (int ct = 0; ct < 4; ct++) acc[rt][ct] = (f32x4)(0.f);

  for (int k0 = 0; k0 < CDIM; k0 += 64){
#pragma unroll
    for (int i = 0; i < 4; i++)
      gload_lds16(ag + (size_t)(i * 64) * CDIM + k0, adst + i * 64 * 64);
#pragma unroll
    for (int j = 0; j < 2; j++)
      gload_lds16(bg + (size_t)(j * 64) * CDIM + k0, bdst + j * 64 * 64);
    __syncthreads();
#pragma unroll
    for (int ks = 0; ks < 2; ks++){
      bf16x8 af[4], bfr[4];
#pragma unroll
      for (int rt = 0; rt < 4; rt++)
        af[rt] = *(const bf16x8*)(As + (wr * 64 + rt * 16 + l15) * 64 + ks * 32 + quad * 8);
#pragma unroll
      for (int ct = 0; ct < 4; ct++)
        bfr[ct] = *(const bf16x8*)(Bs + (wc * 64 + ct * 16 + l15) * 64 + ks * 32 + quad * 8);
#pragma unroll
      for (int rt = 0; rt < 4; rt++)
#pragma unroll
        for (int ct = 0; ct < 4; ct++)
          acc[rt][ct] = mfma16(af[rt], bfr[ct], acc[rt][ct]);
    }
    __syncthreads();
  }

#pragma unroll
  for (int rt = 0; rt < 4; rt++){
#pragma unroll
    for (int q = 0; q < 4; q++){
      float bv = acc[rt][0][q];
      int   bc = c0 + wc * 64 + l15;
#pragma unroll
      for (int ct = 1; ct < 4; ct++){
        float v = acc[rt][ct][q];
        int   c = c0 + wc * 64 + ct * 16 + l15;
        if (v > bv){ bv = v; bc = c; }          // ascending c: first wins ties
      }
#pragma unroll
      for (int off = 1; off <= 8; off <<= 1){
        float ov = __shfl_xor(bv, off, 64);
        int   oc = __shfl_xor(bc, off, 64);
        if (ov > bv || (ov == bv && oc < bc)){ bv = ov; bc = oc; }
      }
      if (l15 == 0){
        int rg = r0 + wr * 64 + rt * 16 + quad * 4 + q;
        u64 key = ((u64)fkey(bv) << 32) | (unsigned int)(~(unsigned int)bc);
        atomicMax(packed + rg, key);
      }
    }
  }
}

// ---------------- K5: per-code gather segment sum (reads packed directly) -
__global__ __launch_bounds__(256) void k_gather(const u64* __restrict__ packed,
                                                const u16* __restrict__ xf,
                                                float* __restrict__ esum,
                                                float* __restrict__ counts){
  __shared__ float part[4][CDIM];   // 8 KB
  __shared__ int   wcnt[4];
  int code = blockIdx.x;
  int tid = threadIdx.x, wave = tid >> 6, lane = tid & 63;
  float acc[8] = {0,0,0,0,0,0,0,0};
  int cnt = 0;
  for (int base = wave * 64; base < NROWS; base += 256){
    u64 pk = packed[base + lane];
    int cl = (int)(~(unsigned int)(pk & 0xffffffffull)) & (KCODES - 1);
    int match = (cl == code);
    u64 mask = __ballot(match);
    cnt += (int)__popcll(mask);
    while (mask){
      int b = __ffsll((long long)mask) - 1;
      mask &= mask - 1;
      int rr = base + b;
      uint4 v = *(const uint4*)(xf + (size_t)rr * CDIM + lane * 8);
      unsigned int w[4] = {v.x, v.y, v.z, v.w};
#pragma unroll
      for (int i = 0; i < 4; i++){
        acc[2 * i]     += bf2f((u16)(w[i] & 0xffffu));
        acc[2 * i + 1] += bf2f((u16)(w[i] >> 16));
      }
    }
  }
#pragma unroll
  for (int j = 0; j < 8; j++) part[wave][lane * 8 + j] = acc[j];
  if (lane == 0) wcnt[wave] = cnt;
  __syncthreads();
  for (int c = tid; c < CDIM; c += 256)
    esum[(size_t)code * CDIM + c] = part[0][c] + part[1][c] + part[2][c] + part[3][c];
  if (tid == 0) counts[code] = (float)(wcnt[0] + wcnt[1] + wcnt[2] + wcnt[3]);
}

// ---------------- K6: new_m = m*0.999 + mean*0.001; normalize -> mn2 bf16 -
__global__ __launch_bounds__(256) void k_newm(const float* __restrict__ m,
                                              const float* __restrict__ esum,
                                              const float* __restrict__ counts,
                                              u16* __restrict__ mn2){
  int row  = blockIdx.x * 4 + (threadIdx.x >> 6);
  int lane = threadIdx.x & 63;
  float cnt = counts[row];
  float sc  = 0.001f / (cnt + 1e-6f);
  float v[8]; float s = 0.f;
#pragma unroll
  for (int i = 0; i < 8; i++){
    int c = lane + i * 64;
    v[i] = m[(size_t)row * CDIM + c] * 0.999f + esum[(size_t)row * CDIM + c] * sc;
    s += v[i] * v[i];
  }
#pragma unroll
  for (int off = 32; off; off >>= 1) s += __shfl_xor(s, off, 64);
  float inv = 1.0f / fmaxf(sqrtf(s), 1e-12f);
#pragma unroll
  for (int i = 0; i < 8; i++) mn2[(size_t)row * CDIM + lane + i * 64] = f2bf(v[i] * inv);
}

// ---------------- K7: GEMM2 score2 = (xf @ mn2^T) / ||x||row --------------
// 256x128 tile, 512 thr, XCD swizzle; epilogue: score2 + psum=Σexp partials
// (no max subtraction: score2 is a cosine similarity, |s|<=~1, exp bounded)
__global__ __launch_bounds__(512, 4) void k_gemm2(const u16* __restrict__ xf,
                                                  const u16* __restrict__ mn2,
                                                  const float* __restrict__ rsum,
                                                  float* __restrict__ score2,
                                                  float* __restrict__ psum){
  __shared__ __align__(16) u16 As[256 * 64];   // 32 KB
  __shared__ __align__(16) u16 Bs[128 * 64];   // 16 KB
  int tid  = threadIdx.x;
  int wave = tid >> 6, lane = tid & 63;
  int wr = wave >> 1, wc = wave & 1;           // 4 x 2 wave grid
  int quad = lane >> 4, l15 = lane & 15;
  int bid  = blockIdx.y * gridDim.x + blockIdx.x;
  int work = (bid & 7) * 128 + (bid >> 3);
  int r0   = (work >> 3) * 256;
  int cidx = work & 7;
  int c0   = cidx * 128;

  int srow = lane >> 3, schunk = lane & 7;
  const u16* ag = xf  + (size_t)(r0 + wave * 8 + srow) * CDIM + schunk * 8;
  const u16* bg = mn2 + (size_t)(c0 + wave * 8 + srow) * CDIM + schunk * 8;
  u16* adst = As + wave * 8 * 64;
  u16* bdst = Bs + wave * 8 * 64;

  f32x4 acc[4][4];
#pragma unroll
  for (int rt = 0; rt < 4; rt++)
#pragma unroll
    for (int ct = 0; ct < 4; ct++) acc[rt][ct] = (f32x4)(0.f);

  for (int k0 = 0; k0 < CDIM; k0 += 64){
#pragma unroll
    for (int i = 0; i < 4; i++)
      gload_lds16(ag + (size_t)(i * 64) * CDIM + k0, adst + i * 64 * 64);
#pragma unroll
    for (int j = 0; j < 2; j++)
      gload_lds16(bg + (size_t)(j * 64) * CDIM + k0, bdst + j * 64 * 64);
    __syncthreads();
#pragma unroll
    for (int ks = 0; ks < 2; ks++){
      bf16x8 af[4], bfr[4];
#pragma unroll
      for (int rt = 0; rt < 4; rt++)
        af[rt] = *(const bf16x8*)(As + (wr * 64 + rt * 16 + l15) * 64 + ks * 32 + quad * 8);
#pragma unroll
      for (int ct = 0; ct < 4; ct++)
        bfr[ct] = *(const bf16x8*)(Bs + (wc * 64 + ct * 16 + l15) * 64 + ks * 32 + quad * 8);
#pragma unroll
      for (int rt = 0; rt < 4; rt++)
#pragma unroll
        for (int ct = 0; ct < 4; ct++)
          acc[rt][ct] = mfma16(af[rt], bfr[ct], acc[rt][ct]);
    }
    __syncthreads();
  }

#pragma unroll
  for (int rt = 0; rt < 4; rt++){
#pragma unroll
    for (int q = 0; q < 4; q++){
      int grow = r0 + wr * 64 + rt * 16 + quad * 4 + q;
      float rv = 1.0f / fmaxf(sqrtf(rsum[grow]), 1e-12f);
      float v0 = acc[rt][0][q] * rv;
      float v1 = acc[rt][1][q] * rv;
      float v2 = acc[rt][2][q] * rv;
      float v3 = acc[rt][3][q] * rv;
      float* so = score2 + (size_t)grow * KCODES + c0 + wc * 64 + l15;
      so[0]  = v0;
      so[16] = v1;
      so[32] = v2;
      so[48] = v3;
      float ss = __expf(v0) + __expf(v1) + __expf(v2) + __expf(v3);
#pragma unroll
      for (int off = 1; off <= 8; off <<= 1) ss += __shfl_xor(ss, off, 64);
      if (l15 == 0) psum[grow * 16 + cidx * 2 + wc] = ss;
    }
  }
}

// ---------------- K8: combine 16 partials/row -> rsinv --------------------
__global__ __launch_bounds__(256) void k_rsinv(const float* __restrict__ psum,
                                               float* __restrict__ rsinv){
  int row = blockIdx.x * 256 + threadIdx.x;
  const float* ps = psum + (size_t)row * 16;
  float S = 0.f;
#pragma unroll
  for (int i = 0; i < 16; i++) S += ps[i];
  rsinv[row] = 1.0f / S;
}

// ---------------- K9: out = (exp(score2) @ std) * rsinv  (128x256, 512 thr)
// A tile reg-staged exp (no max/scale), B via global_load_lds, XCD swizzle.
__global__ __launch_bounds__(512) void k_gemm3(const float* __restrict__ score2,
                                               const float* __restrict__ rsinv,
                                               const u16* __restrict__ stdT,
                                               float* __restrict__ out){
  __shared__ __align__(16) u16 As[128 * LDP];   // 18 KB, padded (ds_write side)
  __shared__ __align__(16) u16 Bs[256 * 64];    // 32 KB, linear (global_load_lds)
  int tid  = threadIdx.x;
  int wave = tid >> 6, lane = tid & 63;
  int wr = wave >> 2, wcol = wave & 3;          // 2 x 4 wave grid
  int quad = lane >> 4, l15 = lane & 15;
  // swizzle: nwg=512 (2 col x 256 row panels); XCD k owns 32 row-panels
  int bid  = blockIdx.y * gridDim.x + blockIdx.x;
  int work = (bid & 7) * 64 + (bid >> 3);
  int r0 = (work >> 1) * 128;
  int c0 = (work & 1) * 256;
  int arow = tid >> 2, aq = tid & 3;            // A: 4 thr/row, 16 elems each

  int srow = lane >> 3, schunk = lane & 7;
  const u16* bg = stdT + (size_t)(c0 + wave * 8 + srow) * KCODES + schunk * 8;
  u16* bdst = Bs + wave * 8 * 64;

  f32x4 acc[4][4];
#pragma unroll
  for (int rt = 0; rt < 4; rt++)
#pragma unroll
    for (int ct = 0; ct < 4; ct++) acc[rt][ct] = (f32x4)(0.f);

  const float* ag = score2 + (size_t)(r0 + arow) * KCODES + aq * 16;

  for (int k0 = 0; k0 < KCODES; k0 += 64){
#pragma unroll
    for (int i = 0; i < 4; i++)
      gload_lds16(bg + (size_t)i * 64 * KCODES + k0, bdst + i * 64 * 64);
#pragma unroll
    for (int j = 0; j < 2; j++){
      float4 a = *(const float4*)(ag + k0 + j * 8);
      float4 b = *(const float4*)(ag + k0 + j * 8 + 4);
      uint4 o;
      o.x = pack2(f2bf(__expf(a.x)), f2bf(__expf(a.y)));
      o.y = pack2(f2bf(__expf(a.z)), f2bf(__expf(a.w)));
      o.z = pack2(f2bf(__expf(b.x)), f2bf(__expf(b.y)));
      o.w = pack2(f2bf(__expf(b.z)), f2bf(__expf(b.w)));
      *(uint4*)(As + arow * LDP + aq * 16 + j * 8) = o;
    }
    __syncthreads();
#pragma unroll
    for (int ks = 0; ks < 2; ks++){
      bf16x8 af[4], bfr[4];
#pragma unroll
      for (int rt = 0; rt < 4; rt++)
        af[rt] = *(const bf16x8*)(As + (wr * 64 + rt * 16 + l15) * LDP + ks * 32 + quad * 8);
#pragma unroll
      for (int ct = 0; ct < 4; ct++)
        bfr[ct] = *(const bf16x8*)(Bs + (wcol * 64 + ct * 16 + l15) * 64 + ks * 32 + quad * 8);
#pragma unroll
      for (int rt = 0; rt < 4; rt++)
#pragma unroll
        for (int ct = 0; ct < 4; ct++)
          acc[rt][ct] = mfma16(af[rt], bfr[ct], acc[rt][ct]);
    }
    __syncthreads();
  }
#pragma unroll
  for (int rt = 0; rt < 4; rt++){
#pragma unroll
    for (int q = 0; q < 4; q++){
      int grow = r0 + wr * 64 + rt * 16 + quad * 4 + q;
      float rs = rsinv[grow];
#pragma unroll
      for (int ct = 0; ct < 4; ct++){
        int gcol = c0 + wcol * 64 + ct * 16 + l15;
        out[(size_t)grow * VC + gcol] = acc[rt][ct][q] * rs;
      }
    }
  }
}

// ---------------- launch ---------------------------------------------------
extern "C" void kernel_launch(void* const* d_in, const int* in_sizes, int n_in,
                              void* d_out, int out_size, void* d_ws, size_t ws_size,
                              hipStream_t stream){
  (void)in_sizes; (void)n_in; (void)out_size; (void)ws_size;
  const float* x      = (const float*)d_in[0];
  const float* m      = (const float*)d_in[1];
  const float* stdmat = (const float*)d_in[2];
  float* out    = (float*)d_out;
  float* score2 = out + (size_t)NROWS * VC;     // outputs: (out, score2)

  char* ws = (char*)d_ws;
  u16*   xf     = (u16*)  (ws + 0);             // 33,554,432 B
  u16*   mn     = (u16*)  (ws + 33554432);      //  1,048,576 B
  u16*   mn2    = (u16*)  (ws + 34603008);      //  1,048,576 B
  u16*   stdT   = (u16*)  (ws + 35651584);      //  1,048,576 B
  u64*   packed = (u64*)  (ws + 36831232);      //    262,144 B
  float* esum   = (float*)(ws + 37224448);      //  2,097,152 B
  float* counts = (float*)(ws + 39321600);      //      4,096 B
  float* rsum   = (float*)(ws + 39325696);      //    131,072 B
  float* rsinv  = (float*)(ws + 39456768);      //    131,072 B
  float* psum   = (float*)(ws + 41684992);      //  2,097,152 B

  hipMemsetAsync(packed, 0, (size_t)NROWS * 8, stream);  // key=0 is identity
  hipMemsetAsync(rsum,   0, (size_t)NROWS * 4, stream);

  k_transpose_x  <<<dim3(64, 8, 8), 256, 0, stream>>>(x, xf, rsum);
  k_prep         <<<768, 256, 0, stream>>>(m, mn, stdmat, stdT);
  k_gemm1_am     <<<dim3(KCODES / 128, NROWS / 256), 512, 0, stream>>>(xf, mn, packed);
  k_gather       <<<KCODES, 256, 0, stream>>>(packed, xf, esum, counts);
  k_newm         <<<KCODES / 4, 256, 0, stream>>>(m, esum, counts, mn2);
  k_gemm2        <<<dim3(KCODES / 128, NROWS / 256), 512, 0, stream>>>(xf, mn2, rsum, score2, psum);
  k_rsinv        <<<NROWS / 256, 256, 0, stream>>>(psum, rsinv);
  k_gemm3        <<<dim3(VC / 256, NROWS / 128), 512, 0, stream>>>(score2, rsinv, stdT, out);
}